// Round 7
// baseline (576.768 us; speedup 1.0000x reference)
//
#include <hip/hip_runtime.h>
#include <hip/hip_fp16.h>
#include <math.h>

#define NN 100000
#define NE 3200000
#define NBKT 782            // ceil(100000 / 128) buckets of 128 dst nodes
#define NCB 1024            // count/scatter blocks (4 blocks/CU)
#define CAP 4608            // max edges per bucket (mean 4092 -> +8 sigma)
#define NBLK_AGG (NN / 16)  // 6250

// ---------------- helpers ----------------

__device__ __forceinline__ uint2 ntload_u2(const uint2* p) {
    unsigned long long v = __builtin_nontemporal_load((const unsigned long long*)p);
    return make_uint2((unsigned)(v & 0xffffffffu), (unsigned)(v >> 32));
}

// ---------------- small init ----------------

__global__ void k_zero_scal(float* __restrict__ scal) {
    if (threadIdx.x < 32) scal[threadIdx.x] = 0.0f;
}

// ---------------- bucket build (no global atomics) ----------------

__global__ void k_count(const int* __restrict__ dst, int* __restrict__ counts) {
    __shared__ int hist[NBKT];
    for (int t = threadIdx.x; t < NBKT; t += 256) hist[t] = 0;
    __syncthreads();
    for (int e = blockIdx.x * 256 + threadIdx.x; e < NE; e += NCB * 256)
        atomicAdd(&hist[__builtin_nontemporal_load(&dst[e]) >> 7], 1);
    __syncthreads();
    for (int t = threadIdx.x; t < NBKT; t += 256)
        counts[blockIdx.x * NBKT + t] = hist[t];
}

__global__ void k_colsum(const int* __restrict__ counts, int* __restrict__ total) {
    int bin = blockIdx.x * 256 + threadIdx.x;
    if (bin >= NBKT) return;
    int s = 0;
    for (int b = 0; b < NCB; ++b) s += counts[b * NBKT + bin];
    total[bin] = s;
}

__global__ void k_scan(const int* __restrict__ total, int* __restrict__ start) {
    __shared__ int a[1024];
    int t = threadIdx.x;
    int mine = (t < NBKT) ? total[t] : 0;
    a[t] = mine;
    for (int off = 1; off < 1024; off <<= 1) {
        __syncthreads();
        int v = a[t] + ((t >= off) ? a[t - off] : 0);
        __syncthreads();
        a[t] = v;
    }
    __syncthreads();
    if (t < NBKT) start[t] = a[t] - mine;        // exclusive
    if (t == 0) start[NBKT] = NE;
}

__global__ void k_base(const int* __restrict__ counts, const int* __restrict__ start,
                       int* __restrict__ base) {
    int bin = blockIdx.x * 256 + threadIdx.x;
    if (bin >= NBKT) return;
    int run = start[bin];
    for (int b = 0; b < NCB; ++b) {
        base[b * NBKT + bin] = run;
        run += counts[b * NBKT + bin];
    }
}

__global__ void k_scatter(const int* __restrict__ src, const int* __restrict__ dst,
                          const float* __restrict__ w, const int* __restrict__ base,
                          uint2* __restrict__ rec) {
    __shared__ int cur[NBKT];
    for (int t = threadIdx.x; t < NBKT; t += 256)
        cur[t] = base[blockIdx.x * NBKT + t];
    __syncthreads();
    for (int e = blockIdx.x * 256 + threadIdx.x; e < NE; e += NCB * 256) {
        int d = __builtin_nontemporal_load(&dst[e]);
        int s = __builtin_nontemporal_load(&src[e]);
        float we = __builtin_nontemporal_load(&w[e]);
        int bin = d >> 7;
        int pos = atomicAdd(&cur[bin], 1);
        rec[pos] = make_uint2(((unsigned)s << 7) | (unsigned)(d & 127),
                              __float_as_uint(we));
    }
}

// ---------------- degree / dinv ----------------

__global__ void k_deg(const uint2* __restrict__ rec, const int* __restrict__ start,
                      float* __restrict__ dinv) {
    __shared__ float dacc[128];
    int bin = blockIdx.x;
    if (threadIdx.x < 128) dacc[threadIdx.x] = 0.0f;
    __syncthreads();
    int e0 = start[bin], e1 = start[bin + 1];
    for (int j = e0 + threadIdx.x; j < e1; j += 256) {
        uint2 r = ntload_u2(&rec[j]);
        atomicAdd(&dacc[r.x & 127], __uint_as_float(r.y));
    }
    __syncthreads();
    int node = (bin << 7) + threadIdx.x;
    if (threadIdx.x < 128 && node < NN)
        dinv[node] = rsqrtf(1.0f + dacc[threadIdx.x]);
}

// ---------------- in-place within-bucket counting sort -> CSR ----------------

__global__ void k_sort(uint2* __restrict__ rec, const int* __restrict__ start,
                       const float* __restrict__ dinv, int* __restrict__ nodeptr) {
    __shared__ uint2 buf[CAP];
    __shared__ int hist[128];
    __shared__ int scn[128];
    __shared__ int cur[128];
    __shared__ float dloc[128];
    int bin = blockIdx.x;
    int base_node = bin << 7;
    int nNodes = min(128, NN - base_node);
    int e0 = start[bin], e1 = start[bin + 1];
    int cnt = e1 - e0;
    if (cnt > CAP) cnt = CAP;
    if (threadIdx.x < 128) {
        hist[threadIdx.x] = 0;
        dloc[threadIdx.x] = (threadIdx.x < nNodes) ? dinv[base_node + threadIdx.x] : 0.0f;
    }
    __syncthreads();
    for (int j = threadIdx.x; j < cnt; j += 256) {
        uint2 r = ntload_u2(&rec[e0 + j]);
        buf[j] = r;
        atomicAdd(&hist[r.x & 127], 1);
    }
    __syncthreads();
    if (threadIdx.x < 128) scn[threadIdx.x] = hist[threadIdx.x];
    __syncthreads();
    for (int off = 1; off < 128; off <<= 1) {
        int v = 0;
        if (threadIdx.x < 128) {
            v = scn[threadIdx.x];
            if (threadIdx.x >= off) v += scn[threadIdx.x - off];
        }
        __syncthreads();
        if (threadIdx.x < 128) scn[threadIdx.x] = v;
        __syncthreads();
    }
    if (threadIdx.x < 128) {
        int excl = scn[threadIdx.x] - hist[threadIdx.x];
        cur[threadIdx.x] = excl;
        if (threadIdx.x < nNodes) nodeptr[base_node + threadIdx.x] = e0 + excl;
    }
    if (bin == NBKT - 1 && threadIdx.x == 0) nodeptr[NN] = e1;
    __syncthreads();
    for (int j = threadIdx.x; j < cnt; j += 256) {
        uint2 r = buf[j];
        int s = (int)(r.x >> 7);
        int dl = r.x & 127;
        int pos = atomicAdd(&cur[dl], 1);
        float nw = dinv[s] * __uint_as_float(r.y) * dloc[dl];
        rec[e0 + pos] = make_uint2((unsigned)s, __float_as_uint(nw));
    }
}

// ---------------- dense transform layer 1 (LDS-staged, fp16 out) ----------------

__global__ __launch_bounds__(256) void k_xform64(const float* __restrict__ x,
                                                 const float* __restrict__ W,
                                                 __half* __restrict__ out) {
    __shared__ float xs[64 * 68];
    __shared__ float Wsh[16 * 68];
    int row0 = blockIdx.x * 64;
    for (int idx = threadIdx.x; idx < 1024; idx += 256)
        Wsh[(idx >> 6) * 68 + (idx & 63)] = W[idx];
    for (int idx = threadIdx.x; idx < 1024; idx += 256) {
        int r = idx >> 4, c4 = idx & 15;
        float4 v = make_float4(0.f, 0.f, 0.f, 0.f);
        if (row0 + r < NN)
            v = *(const float4*)(x + (size_t)(row0 + r) * 64 + c4 * 4);
        *(float4*)&xs[r * 68 + c4 * 4] = v;
    }
    __syncthreads();
    int f = threadIdx.x & 15, rg = threadIdx.x >> 4;
    float a0 = 0.f, a1 = 0.f, a2 = 0.f, a3 = 0.f;
#pragma unroll
    for (int k4 = 0; k4 < 16; ++k4) {
        float4 wv = *(float4*)&Wsh[f * 68 + k4 * 4];
        float4 x0 = *(float4*)&xs[(rg * 4 + 0) * 68 + k4 * 4];
        float4 x1 = *(float4*)&xs[(rg * 4 + 1) * 68 + k4 * 4];
        float4 x2 = *(float4*)&xs[(rg * 4 + 2) * 68 + k4 * 4];
        float4 x3 = *(float4*)&xs[(rg * 4 + 3) * 68 + k4 * 4];
        a0 += x0.x * wv.x + x0.y * wv.y + x0.z * wv.z + x0.w * wv.w;
        a1 += x1.x * wv.x + x1.y * wv.y + x1.z * wv.z + x1.w * wv.w;
        a2 += x2.x * wv.x + x2.y * wv.y + x2.z * wv.z + x2.w * wv.w;
        a3 += x3.x * wv.x + x3.y * wv.y + x3.z * wv.z + x3.w * wv.w;
    }
    int br = row0 + rg * 4;
    if (br + 0 < NN) out[(br + 0) * 16 + f] = __float2half(a0);
    if (br + 1 < NN) out[(br + 1) * 16 + f] = __float2half(a1);
    if (br + 2 < NN) out[(br + 2) * 16 + f] = __float2half(a2);
    if (br + 3 < NN) out[(br + 3) * 16 + f] = __float2half(a3);
}

// ---------------- edge-gather core (unroll-8 software pipeline) ----------------

__device__ __forceinline__ float edge_gather16(const uint2* __restrict__ rec,
                                               int e0, int e1, int f,
                                               const __half* __restrict__ h,
                                               float acc) {
    int j = e0;
    uint2 p[8];
    if (j + 8 <= e1) {
#pragma unroll
        for (int t = 0; t < 8; ++t) p[t] = ntload_u2(&rec[j + t]);
        j += 8;
        for (; j + 8 <= e1; j += 8) {
            uint2 q[8];
#pragma unroll
            for (int t = 0; t < 8; ++t) q[t] = ntload_u2(&rec[j + t]);
#pragma unroll
            for (int t = 0; t < 8; ++t)
                acc += __uint_as_float(p[t].y) * __half2float(h[p[t].x * 16 + f]);
#pragma unroll
            for (int t = 0; t < 8; ++t) p[t] = q[t];
        }
#pragma unroll
        for (int t = 0; t < 8; ++t)
            acc += __uint_as_float(p[t].y) * __half2float(h[p[t].x * 16 + f]);
    }
    for (; j < e1; ++j) {
        uint2 r = ntload_u2(&rec[j]);
        acc += __uint_as_float(r.y) * __half2float(h[r.x * 16 + f]);
    }
    return acc;
}

// ---------------- layer 1: CSR agg + fused relu + W2 transform ----------------

__global__ __launch_bounds__(256) void k_agg16_l1(const uint2* __restrict__ rec,
                                                  const int* __restrict__ nodeptr,
                                                  const float* __restrict__ dinv,
                                                  const __half* __restrict__ h,
                                                  const float* __restrict__ b1,
                                                  const float* __restrict__ W2,
                                                  __half* __restrict__ outC) {
    __shared__ float W2s[16 * 17];
    for (int idx = threadIdx.x; idx < 256; idx += 256)
        W2s[(idx >> 4) * 17 + (idx & 15)] = W2[idx];
    __syncthreads();
    int f = threadIdx.x & 15;
    int n = blockIdx.x * 16 + (threadIdx.x >> 4);
    int e0 = nodeptr[n], e1 = nodeptr[n + 1];
    float di = dinv[n];
    float acc = b1[f] + di * di * __half2float(h[n * 16 + f]);
    acc = edge_gather16(rec, e0, e1, f, h, acc);
    float rl = fmaxf(acc, 0.0f);
    float a2 = 0.0f;
#pragma unroll
    for (int k = 0; k < 16; ++k)
        a2 += __shfl(rl, k, 16) * W2s[f * 17 + k];
    outC[n * 16 + f] = __float2half(a2);
}

// ---------------- layer 2: CSR agg + relu + W3 dot + pool partials ----------------

__global__ __launch_bounds__(256) void k_agg16_l2(const uint2* __restrict__ rec,
                                                  const int* __restrict__ nodeptr,
                                                  const float* __restrict__ dinv,
                                                  const __half* __restrict__ h,
                                                  const float* __restrict__ b2,
                                                  const float* __restrict__ W3,
                                                  float* __restrict__ clin,
                                                  float* __restrict__ partials) {
    __shared__ float lds[256];
    int f = threadIdx.x & 15;
    int n = blockIdx.x * 16 + (threadIdx.x >> 4);
    int e0 = nodeptr[n], e1 = nodeptr[n + 1];
    float di = dinv[n];
    float acc = b2[f] + di * di * __half2float(h[n * 16 + f]);
    acc = edge_gather16(rec, e0, e1, f, h, acc);
    float rl = fmaxf(acc, 0.0f);
    // clin[n] = relu(o2) . W3
    float s = rl * W3[f];
    s += __shfl_xor(s, 8, 16);
    s += __shfl_xor(s, 4, 16);
    s += __shfl_xor(s, 2, 16);
    s += __shfl_xor(s, 1, 16);
    if (f == 0) clin[n] = s;
    // pool partials: per-block per-feature sums, NO global atomics
    lds[threadIdx.x] = rl;
    __syncthreads();
    for (int st = 128; st >= 16; st >>= 1) {
        if (threadIdx.x < st) lds[threadIdx.x] += lds[threadIdx.x + st];
        __syncthreads();
    }
    if (threadIdx.x < 16) partials[blockIdx.x * 16 + threadIdx.x] = lds[threadIdx.x];
}

// ---------------- layer 3 scalar aggregation + fused max ----------------

__device__ __forceinline__ unsigned fkey(float x) {
    unsigned b = __float_as_uint(x);
    return (b & 0x80000000u) ? ~b : (b | 0x80000000u);
}
__device__ __forceinline__ float fdecode(unsigned u) {
    unsigned b = (u & 0x80000000u) ? (u & 0x7FFFFFFFu) : ~u;
    return __uint_as_float(b);
}

__global__ __launch_bounds__(256) void k_aggc(const uint2* __restrict__ rec,
                                              const int* __restrict__ nodeptr,
                                              const float* __restrict__ dinv,
                                              const float* __restrict__ clin,
                                              const float* __restrict__ b3,
                                              float* __restrict__ c,
                                              unsigned* __restrict__ maxkey) {
    __shared__ float smax[32];
    int lane = threadIdx.x & 7;
    int g = threadIdx.x >> 3;                       // 32 node-groups
    int n = blockIdx.x * 32 + g;
    int e0 = nodeptr[n], e1 = nodeptr[n + 1];
    float acc = 0.0f;
    int j = e0 + lane;
    if (j < e1) {
        uint2 p = ntload_u2(&rec[j]);
        j += 8;
        while (j < e1) {
            uint2 q = ntload_u2(&rec[j]);
            j += 8;
            acc += __uint_as_float(p.y) * clin[p.x];
            p = q;
        }
        acc += __uint_as_float(p.y) * clin[p.x];
    }
    acc += __shfl_down(acc, 4, 8);
    acc += __shfl_down(acc, 2, 8);
    acc += __shfl_down(acc, 1, 8);
    if (lane == 0) {
        float di = dinv[n];
        float cv = b3[0] + di * di * clin[n] + acc;
        c[n] = cv;
        smax[g] = cv;
    }
    __syncthreads();
    if (threadIdx.x < 32) {
        float m = smax[threadIdx.x];
        m = fmaxf(m, __shfl_xor(m, 16, 32));
        m = fmaxf(m, __shfl_xor(m, 8, 32));
        m = fmaxf(m, __shfl_xor(m, 4, 32));
        m = fmaxf(m, __shfl_xor(m, 2, 32));
        m = fmaxf(m, __shfl_xor(m, 1, 32));
        if (threadIdx.x == 0) atomicMax(maxkey, fkey(m));
    }
}

// ---------------- softmax ----------------

__global__ void k_exp(const float* __restrict__ c, const unsigned* __restrict__ maxkey,
                      float* __restrict__ outp, float* __restrict__ sumexp) {
    __shared__ float lds[256];
    float mx = fdecode(*maxkey);
    float s = 0.0f;
    for (int i = blockIdx.x * 256 + threadIdx.x; i < NN; i += gridDim.x * 256) {
        float p = expf(c[i] - mx);
        outp[i] = p;
        s += p;
    }
    lds[threadIdx.x] = s;
    __syncthreads();
    for (int t = 128; t > 0; t >>= 1) {
        if (threadIdx.x < t) lds[threadIdx.x] += lds[threadIdx.x + t];
        __syncthreads();
    }
    if (threadIdx.x == 0) atomicAdd(sumexp, lds[0]);
}

__global__ void k_final(float* __restrict__ out, const float* __restrict__ sumexp,
                        const float* __restrict__ partials, const float* __restrict__ A2w,
                        const float* __restrict__ A2b) {
    __shared__ float lds[256];
    float inv = 1.0f / (*sumexp);
    for (int i = blockIdx.x * 256 + threadIdx.x; i < NN; i += gridDim.x * 256)
        out[i] *= inv;
    if (blockIdx.x == 0) {
        int f = threadIdx.x & 15, g = threadIdx.x >> 4;   // 16 groups x 16 feats
        float s = 0.0f;
        for (int i = g; i < NBLK_AGG; i += 16) s += partials[i * 16 + f];
        lds[threadIdx.x] = s;
        __syncthreads();
        for (int st = 128; st >= 16; st >>= 1) {
            if (threadIdx.x < st) lds[threadIdx.x] += lds[threadIdx.x + st];
            __syncthreads();
        }
        if (threadIdx.x == 0) {
            float v = 0.0f;
#pragma unroll
            for (int ff = 0; ff < 16; ++ff) v += lds[ff] * (1.0f / (float)NN) * A2w[ff];
            out[NN] = v + A2b[0];
        }
    }
}

// ---------------- launch ----------------

extern "C" void kernel_launch(void* const* d_in, const int* in_sizes, int n_in,
                              void* d_out, int out_size, void* d_ws, size_t ws_size,
                              hipStream_t stream) {
    const float* x   = (const float*)d_in[0];
    const int*   src = (const int*)d_in[1];
    const int*   dst = ((const int*)d_in[1]) + NE;
    const float* w   = (const float*)d_in[2];
    const float* W1  = (const float*)d_in[3];
    const float* b1  = (const float*)d_in[4];
    const float* W2  = (const float*)d_in[5];
    const float* b2  = (const float*)d_in[6];
    const float* W3  = (const float*)d_in[7];
    const float* b3  = (const float*)d_in[8];
    const float* A2w = (const float*)d_in[9];
    const float* A2b = (const float*)d_in[10];
    float* out = (float*)d_out;

    // workspace layout (~40.4 MB; proven ws >= 46.4 MB)
    float* cur = (float*)d_ws;
    uint2*  rec     = (uint2*)cur;      cur += 2 * (size_t)NE;   // 25.6 MB
    float*  dinv    = cur;              cur += NN;
    __half* bufA    = (__half*)cur;     cur += NN * 8;           // NN*16 fp16
    __half* bufC    = (__half*)cur;     cur += NN * 8;           // NN*16 fp16
    float*  clin    = cur;              cur += NN;
    float*  cbuf    = cur;              cur += NN;
    float*  scal    = cur;              cur += 32;               // [0]=maxkey [1]=sumexp
    int*    total   = (int*)cur;        cur += NBKT;
    int*    startb  = (int*)cur;        cur += NBKT + 1;
    int*    nodeptr = (int*)cur;        cur += NN + 1;
    float*  partials= cur;              cur += (size_t)NBLK_AGG * 16;  // 400 KB
    int*    counts  = (int*)cur;        cur += (size_t)NCB * NBKT;     // 3.2 MB
    int*    basea   = (int*)cur;        cur += (size_t)NCB * NBKT;     // 3.2 MB

    // bucket build + degree + CSR sort
    k_zero_scal<<<1, 64, 0, stream>>>(scal);
    k_count<<<NCB, 256, 0, stream>>>(dst, counts);
    k_colsum<<<(NBKT + 255) / 256, 256, 0, stream>>>(counts, total);
    k_scan<<<1, 1024, 0, stream>>>(total, startb);
    k_base<<<(NBKT + 255) / 256, 256, 0, stream>>>(counts, startb, basea);
    k_scatter<<<NCB, 256, 0, stream>>>(src, dst, w, basea, rec);
    k_deg<<<NBKT, 256, 0, stream>>>(rec, startb, dinv);
    k_sort<<<NBKT, 256, 0, stream>>>(rec, startb, dinv, nodeptr);

    // layer 1 dense (fp16 out)
    k_xform64<<<(NN + 63) / 64, 256, 0, stream>>>(x, W1, bufA);
    // layer 1 agg + fused relu + W2 (fp16 in/out)
    k_agg16_l1<<<NBLK_AGG, 256, 0, stream>>>(rec, nodeptr, dinv, bufA, b1, W2, bufC);
    // layer 2 agg + fused relu + W3 dot + pool partials
    k_agg16_l2<<<NBLK_AGG, 256, 0, stream>>>(rec, nodeptr, dinv, bufC, b2, W3, clin, partials);
    // layer 3 scalar agg + fused max
    k_aggc<<<NN / 32, 256, 0, stream>>>(rec, nodeptr, dinv, clin, b3, cbuf, (unsigned*)scal);

    // softmax + value
    k_exp<<<512, 256, 0, stream>>>(cbuf, (const unsigned*)scal, out, scal + 1);
    k_final<<<512, 256, 0, stream>>>(out, scal + 1, partials, A2w, A2b);
}

// Round 8
// 486.326 us; speedup vs baseline: 1.1860x; 1.1860x over previous
//
#include <hip/hip_runtime.h>
#include <hip/hip_fp16.h>
#include <math.h>

#define NN 100000
#define NE 3200000
#define NBKT 782            // ceil(100000 / 128) buckets of 128 dst nodes
#define NCB 1024            // count/scatter blocks (4 blocks/CU)
#define CAP 4608            // max edges per bucket (mean 4092 -> +8 sigma)
#define NBLK_AGG (NN / 16)  // 6250

// ---------------- helpers ----------------

__device__ __forceinline__ uint2 ntload_u2(const uint2* p) {
    unsigned long long v = __builtin_nontemporal_load((const unsigned long long*)p);
    return make_uint2((unsigned)(v & 0xffffffffu), (unsigned)(v >> 32));
}

// ---------------- small init ----------------

__global__ void k_zero_scal(float* __restrict__ scal) {
    if (threadIdx.x < 32) scal[threadIdx.x] = 0.0f;
}

// ---------------- bucket build (no global atomics) ----------------

__global__ void k_count(const int* __restrict__ dst, int* __restrict__ counts) {
    __shared__ int hist[NBKT];
    for (int t = threadIdx.x; t < NBKT; t += 256) hist[t] = 0;
    __syncthreads();
    for (int e = blockIdx.x * 256 + threadIdx.x; e < NE; e += NCB * 256)
        atomicAdd(&hist[__builtin_nontemporal_load(&dst[e]) >> 7], 1);
    __syncthreads();
    for (int t = threadIdx.x; t < NBKT; t += 256)
        counts[blockIdx.x * NBKT + t] = hist[t];
}

__global__ void k_colsum(const int* __restrict__ counts, int* __restrict__ total) {
    int bin = blockIdx.x * 256 + threadIdx.x;
    if (bin >= NBKT) return;
    int s = 0;
    for (int b = 0; b < NCB; ++b) s += counts[b * NBKT + bin];
    total[bin] = s;
}

__global__ void k_scan(const int* __restrict__ total, int* __restrict__ start) {
    __shared__ int a[1024];
    int t = threadIdx.x;
    int mine = (t < NBKT) ? total[t] : 0;
    a[t] = mine;
    for (int off = 1; off < 1024; off <<= 1) {
        __syncthreads();
        int v = a[t] + ((t >= off) ? a[t - off] : 0);
        __syncthreads();
        a[t] = v;
    }
    __syncthreads();
    if (t < NBKT) start[t] = a[t] - mine;        // exclusive
    if (t == 0) start[NBKT] = NE;
}

__global__ void k_base(const int* __restrict__ counts, const int* __restrict__ start,
                       int* __restrict__ base) {
    int bin = blockIdx.x * 256 + threadIdx.x;
    if (bin >= NBKT) return;
    int run = start[bin];
    for (int b = 0; b < NCB; ++b) {
        base[b * NBKT + bin] = run;
        run += counts[b * NBKT + bin];
    }
}

__global__ void k_scatter(const int* __restrict__ src, const int* __restrict__ dst,
                          const float* __restrict__ w, const int* __restrict__ base,
                          uint2* __restrict__ rec) {
    __shared__ int cur[NBKT];
    for (int t = threadIdx.x; t < NBKT; t += 256)
        cur[t] = base[blockIdx.x * NBKT + t];
    __syncthreads();
    for (int e = blockIdx.x * 256 + threadIdx.x; e < NE; e += NCB * 256) {
        int d = __builtin_nontemporal_load(&dst[e]);
        int s = __builtin_nontemporal_load(&src[e]);
        float we = __builtin_nontemporal_load(&w[e]);
        int bin = d >> 7;
        int pos = atomicAdd(&cur[bin], 1);
        rec[pos] = make_uint2(((unsigned)s << 7) | (unsigned)(d & 127),
                              __float_as_uint(we));
    }
}

// ---------------- degree / dinv ----------------

__global__ void k_deg(const uint2* __restrict__ rec, const int* __restrict__ start,
                      float* __restrict__ dinv) {
    __shared__ float dacc[128];
    int bin = blockIdx.x;
    if (threadIdx.x < 128) dacc[threadIdx.x] = 0.0f;
    __syncthreads();
    int e0 = start[bin], e1 = start[bin + 1];
    for (int j = e0 + threadIdx.x; j < e1; j += 256) {
        uint2 r = ntload_u2(&rec[j]);
        atomicAdd(&dacc[r.x & 127], __uint_as_float(r.y));
    }
    __syncthreads();
    int node = (bin << 7) + threadIdx.x;
    if (threadIdx.x < 128 && node < NN)
        dinv[node] = rsqrtf(1.0f + dacc[threadIdx.x]);
}

// ---------------- in-place within-bucket counting sort -> CSR ----------------

__global__ void k_sort(uint2* __restrict__ rec, const int* __restrict__ start,
                       const float* __restrict__ dinv, int* __restrict__ nodeptr) {
    __shared__ uint2 buf[CAP];
    __shared__ int hist[128];
    __shared__ int scn[128];
    __shared__ int cur[128];
    __shared__ float dloc[128];
    int bin = blockIdx.x;
    int base_node = bin << 7;
    int nNodes = min(128, NN - base_node);
    int e0 = start[bin], e1 = start[bin + 1];
    int cnt = e1 - e0;
    if (cnt > CAP) cnt = CAP;
    if (threadIdx.x < 128) {
        hist[threadIdx.x] = 0;
        dloc[threadIdx.x] = (threadIdx.x < nNodes) ? dinv[base_node + threadIdx.x] : 0.0f;
    }
    __syncthreads();
    for (int j = threadIdx.x; j < cnt; j += 256) {
        uint2 r = ntload_u2(&rec[e0 + j]);
        buf[j] = r;
        atomicAdd(&hist[r.x & 127], 1);
    }
    __syncthreads();
    if (threadIdx.x < 128) scn[threadIdx.x] = hist[threadIdx.x];
    __syncthreads();
    for (int off = 1; off < 128; off <<= 1) {
        int v = 0;
        if (threadIdx.x < 128) {
            v = scn[threadIdx.x];
            if (threadIdx.x >= off) v += scn[threadIdx.x - off];
        }
        __syncthreads();
        if (threadIdx.x < 128) scn[threadIdx.x] = v;
        __syncthreads();
    }
    if (threadIdx.x < 128) {
        int excl = scn[threadIdx.x] - hist[threadIdx.x];
        cur[threadIdx.x] = excl;
        if (threadIdx.x < nNodes) nodeptr[base_node + threadIdx.x] = e0 + excl;
    }
    if (bin == NBKT - 1 && threadIdx.x == 0) nodeptr[NN] = e1;
    __syncthreads();
    for (int j = threadIdx.x; j < cnt; j += 256) {
        uint2 r = buf[j];
        int s = (int)(r.x >> 7);
        int dl = r.x & 127;
        int pos = atomicAdd(&cur[dl], 1);
        float nw = dinv[s] * __uint_as_float(r.y) * dloc[dl];
        rec[e0 + pos] = make_uint2((unsigned)s, __float_as_uint(nw));
    }
}

// ---------------- dense transform layer 1 (LDS-staged, fp16 out) ----------------

__global__ __launch_bounds__(256) void k_xform64(const float* __restrict__ x,
                                                 const float* __restrict__ W,
                                                 __half* __restrict__ out) {
    __shared__ float xs[64 * 68];
    __shared__ float Wsh[16 * 68];
    int row0 = blockIdx.x * 64;
    for (int idx = threadIdx.x; idx < 1024; idx += 256)
        Wsh[(idx >> 6) * 68 + (idx & 63)] = W[idx];
    for (int idx = threadIdx.x; idx < 1024; idx += 256) {
        int r = idx >> 4, c4 = idx & 15;
        float4 v = make_float4(0.f, 0.f, 0.f, 0.f);
        if (row0 + r < NN)
            v = *(const float4*)(x + (size_t)(row0 + r) * 64 + c4 * 4);
        *(float4*)&xs[r * 68 + c4 * 4] = v;
    }
    __syncthreads();
    int f = threadIdx.x & 15, rg = threadIdx.x >> 4;
    float a0 = 0.f, a1 = 0.f, a2 = 0.f, a3 = 0.f;
#pragma unroll
    for (int k4 = 0; k4 < 16; ++k4) {
        float4 wv = *(float4*)&Wsh[f * 68 + k4 * 4];
        float4 x0 = *(float4*)&xs[(rg * 4 + 0) * 68 + k4 * 4];
        float4 x1 = *(float4*)&xs[(rg * 4 + 1) * 68 + k4 * 4];
        float4 x2 = *(float4*)&xs[(rg * 4 + 2) * 68 + k4 * 4];
        float4 x3 = *(float4*)&xs[(rg * 4 + 3) * 68 + k4 * 4];
        a0 += x0.x * wv.x + x0.y * wv.y + x0.z * wv.z + x0.w * wv.w;
        a1 += x1.x * wv.x + x1.y * wv.y + x1.z * wv.z + x1.w * wv.w;
        a2 += x2.x * wv.x + x2.y * wv.y + x2.z * wv.z + x2.w * wv.w;
        a3 += x3.x * wv.x + x3.y * wv.y + x3.z * wv.z + x3.w * wv.w;
    }
    int br = row0 + rg * 4;
    if (br + 0 < NN) out[(br + 0) * 16 + f] = __float2half(a0);
    if (br + 1 < NN) out[(br + 1) * 16 + f] = __float2half(a1);
    if (br + 2 < NN) out[(br + 2) * 16 + f] = __float2half(a2);
    if (br + 3 < NN) out[(br + 3) * 16 + f] = __float2half(a3);
}

// ---------------- edge-gather core (unroll-8 software pipeline) ----------------

__device__ __forceinline__ float edge_gather16(const uint2* __restrict__ rec,
                                               int e0, int e1, int f,
                                               const __half* __restrict__ h,
                                               float acc) {
    int j = e0;
    uint2 p[8];
    if (j + 8 <= e1) {
#pragma unroll
        for (int t = 0; t < 8; ++t) p[t] = ntload_u2(&rec[j + t]);
        j += 8;
        for (; j + 8 <= e1; j += 8) {
            uint2 q[8];
#pragma unroll
            for (int t = 0; t < 8; ++t) q[t] = ntload_u2(&rec[j + t]);
#pragma unroll
            for (int t = 0; t < 8; ++t)
                acc += __uint_as_float(p[t].y) * __half2float(h[p[t].x * 16 + f]);
#pragma unroll
            for (int t = 0; t < 8; ++t) p[t] = q[t];
        }
#pragma unroll
        for (int t = 0; t < 8; ++t)
            acc += __uint_as_float(p[t].y) * __half2float(h[p[t].x * 16 + f]);
    }
    for (; j < e1; ++j) {
        uint2 r = ntload_u2(&rec[j]);
        acc += __uint_as_float(r.y) * __half2float(h[r.x * 16 + f]);
    }
    return acc;
}

// ---------------- layer 1: CSR agg + fused relu + W2 transform ----------------

__global__ __launch_bounds__(256) void k_agg16_l1(const uint2* __restrict__ rec,
                                                  const int* __restrict__ nodeptr,
                                                  const float* __restrict__ dinv,
                                                  const __half* __restrict__ h,
                                                  const float* __restrict__ b1,
                                                  const float* __restrict__ W2,
                                                  __half* __restrict__ outC) {
    __shared__ float W2s[16 * 17];
    for (int idx = threadIdx.x; idx < 256; idx += 256)
        W2s[(idx >> 4) * 17 + (idx & 15)] = W2[idx];
    __syncthreads();
    int f = threadIdx.x & 15;
    int n = blockIdx.x * 16 + (threadIdx.x >> 4);
    int e0 = nodeptr[n], e1 = nodeptr[n + 1];
    float di = dinv[n];
    float acc = b1[f] + di * di * __half2float(h[n * 16 + f]);
    acc = edge_gather16(rec, e0, e1, f, h, acc);
    float rl = fmaxf(acc, 0.0f);
    float a2 = 0.0f;
#pragma unroll
    for (int k = 0; k < 16; ++k)
        a2 += __shfl(rl, k, 16) * W2s[f * 17 + k];
    outC[n * 16 + f] = __float2half(a2);
}

// ---------------- layer 2: CSR agg + relu + W3 dot + pool partials ----------------

__global__ __launch_bounds__(256) void k_agg16_l2(const uint2* __restrict__ rec,
                                                  const int* __restrict__ nodeptr,
                                                  const float* __restrict__ dinv,
                                                  const __half* __restrict__ h,
                                                  const float* __restrict__ b2,
                                                  const float* __restrict__ W3,
                                                  float* __restrict__ clin,
                                                  float* __restrict__ partials) {
    __shared__ float lds[256];
    int f = threadIdx.x & 15;
    int n = blockIdx.x * 16 + (threadIdx.x >> 4);
    int e0 = nodeptr[n], e1 = nodeptr[n + 1];
    float di = dinv[n];
    float acc = b2[f] + di * di * __half2float(h[n * 16 + f]);
    acc = edge_gather16(rec, e0, e1, f, h, acc);
    float rl = fmaxf(acc, 0.0f);
    // clin[n] = relu(o2) . W3
    float s = rl * W3[f];
    s += __shfl_xor(s, 8, 16);
    s += __shfl_xor(s, 4, 16);
    s += __shfl_xor(s, 2, 16);
    s += __shfl_xor(s, 1, 16);
    if (f == 0) clin[n] = s;
    // pool partials: per-block per-feature sums, NO global atomics
    lds[threadIdx.x] = rl;
    __syncthreads();
    for (int st = 128; st >= 16; st >>= 1) {
        if (threadIdx.x < st) lds[threadIdx.x] += lds[threadIdx.x + st];
        __syncthreads();
    }
    if (threadIdx.x < 16) partials[blockIdx.x * 16 + threadIdx.x] = lds[threadIdx.x];
}

// ---------------- partials reduction (grid-wide, was the 100us serial bug) ----------------

__global__ __launch_bounds__(256) void k_psum(const float* __restrict__ partials,
                                              float* __restrict__ hsum) {
    __shared__ float lds[256];
    int f = threadIdx.x & 15, g = threadIdx.x >> 4;    // 16 row-groups x 16 feats
    const int rows_per_blk = (NBLK_AGG + 63) / 64;     // 98
    int r0 = blockIdx.x * rows_per_blk;
    int r1 = min(r0 + rows_per_blk, NBLK_AGG);
    float s = 0.0f;
    for (int i = r0 + g; i < r1; i += 16) s += partials[i * 16 + f];
    lds[threadIdx.x] = s;
    __syncthreads();
    for (int st = 128; st >= 16; st >>= 1) {
        if (threadIdx.x < st) lds[threadIdx.x] += lds[threadIdx.x + st];
        __syncthreads();
    }
    if (threadIdx.x < 16) atomicAdd(&hsum[threadIdx.x], lds[threadIdx.x]);
}

// ---------------- layer 3 scalar aggregation + fused max ----------------

__device__ __forceinline__ unsigned fkey(float x) {
    unsigned b = __float_as_uint(x);
    return (b & 0x80000000u) ? ~b : (b | 0x80000000u);
}
__device__ __forceinline__ float fdecode(unsigned u) {
    unsigned b = (u & 0x80000000u) ? (u & 0x7FFFFFFFu) : ~u;
    return __uint_as_float(b);
}

__global__ __launch_bounds__(256) void k_aggc(const uint2* __restrict__ rec,
                                              const int* __restrict__ nodeptr,
                                              const float* __restrict__ dinv,
                                              const float* __restrict__ clin,
                                              const float* __restrict__ b3,
                                              float* __restrict__ c,
                                              unsigned* __restrict__ maxkey) {
    __shared__ float smax[32];
    int lane = threadIdx.x & 7;
    int g = threadIdx.x >> 3;                       // 32 node-groups
    int n = blockIdx.x * 32 + g;
    int e0 = nodeptr[n], e1 = nodeptr[n + 1];
    float acc = 0.0f;
    int j = e0 + lane;
    if (j < e1) {
        uint2 p = ntload_u2(&rec[j]);
        j += 8;
        while (j < e1) {
            uint2 q = ntload_u2(&rec[j]);
            j += 8;
            acc += __uint_as_float(p.y) * clin[p.x];
            p = q;
        }
        acc += __uint_as_float(p.y) * clin[p.x];
    }
    acc += __shfl_down(acc, 4, 8);
    acc += __shfl_down(acc, 2, 8);
    acc += __shfl_down(acc, 1, 8);
    if (lane == 0) {
        float di = dinv[n];
        float cv = b3[0] + di * di * clin[n] + acc;
        c[n] = cv;
        smax[g] = cv;
    }
    __syncthreads();
    if (threadIdx.x < 32) {
        float m = smax[threadIdx.x];
        m = fmaxf(m, __shfl_xor(m, 16, 32));
        m = fmaxf(m, __shfl_xor(m, 8, 32));
        m = fmaxf(m, __shfl_xor(m, 4, 32));
        m = fmaxf(m, __shfl_xor(m, 2, 32));
        m = fmaxf(m, __shfl_xor(m, 1, 32));
        if (threadIdx.x == 0) atomicMax(maxkey, fkey(m));
    }
}

// ---------------- softmax ----------------

__global__ void k_exp(const float* __restrict__ c, const unsigned* __restrict__ maxkey,
                      float* __restrict__ outp, float* __restrict__ sumexp) {
    __shared__ float lds[256];
    float mx = fdecode(*maxkey);
    float s = 0.0f;
    for (int i = blockIdx.x * 256 + threadIdx.x; i < NN; i += gridDim.x * 256) {
        float p = expf(c[i] - mx);
        outp[i] = p;
        s += p;
    }
    lds[threadIdx.x] = s;
    __syncthreads();
    for (int t = 128; t > 0; t >>= 1) {
        if (threadIdx.x < t) lds[threadIdx.x] += lds[threadIdx.x + t];
        __syncthreads();
    }
    if (threadIdx.x == 0) atomicAdd(sumexp, lds[0]);
}

__global__ void k_final(float* __restrict__ out, const float* __restrict__ sumexp,
                        const float* __restrict__ hsum, const float* __restrict__ A2w,
                        const float* __restrict__ A2b) {
    float inv = 1.0f / (*sumexp);
    for (int i = blockIdx.x * 256 + threadIdx.x; i < NN; i += gridDim.x * 256)
        out[i] *= inv;
    if (blockIdx.x == 0 && threadIdx.x == 0) {
        float v = 0.0f;
#pragma unroll
        for (int f = 0; f < 16; ++f) v += hsum[f] * (1.0f / (float)NN) * A2w[f];
        out[NN] = v + A2b[0];
    }
}

// ---------------- launch ----------------

extern "C" void kernel_launch(void* const* d_in, const int* in_sizes, int n_in,
                              void* d_out, int out_size, void* d_ws, size_t ws_size,
                              hipStream_t stream) {
    const float* x   = (const float*)d_in[0];
    const int*   src = (const int*)d_in[1];
    const int*   dst = ((const int*)d_in[1]) + NE;
    const float* w   = (const float*)d_in[2];
    const float* W1  = (const float*)d_in[3];
    const float* b1  = (const float*)d_in[4];
    const float* W2  = (const float*)d_in[5];
    const float* b2  = (const float*)d_in[6];
    const float* W3  = (const float*)d_in[7];
    const float* b3  = (const float*)d_in[8];
    const float* A2w = (const float*)d_in[9];
    const float* A2b = (const float*)d_in[10];
    float* out = (float*)d_out;

    // workspace layout
    float* cur = (float*)d_ws;
    uint2*  rec     = (uint2*)cur;      cur += 2 * (size_t)NE;   // 25.6 MB
    float*  dinv    = cur;              cur += NN;
    __half* bufA    = (__half*)cur;     cur += NN * 8;           // NN*16 fp16
    __half* bufC    = (__half*)cur;     cur += NN * 8;           // NN*16 fp16
    float*  clin    = cur;              cur += NN;
    float*  cbuf    = cur;              cur += NN;
    float*  scal    = cur;              cur += 32;   // [0]=maxkey [1]=sumexp [2..17]=hsum
    int*    total   = (int*)cur;        cur += NBKT;
    int*    startb  = (int*)cur;        cur += NBKT + 1;
    int*    nodeptr = (int*)cur;        cur += NN + 1;
    float*  partials= cur;              cur += (size_t)NBLK_AGG * 16;  // 400 KB
    int*    counts  = (int*)cur;        cur += (size_t)NCB * NBKT;     // 3.2 MB
    int*    basea   = (int*)cur;        cur += (size_t)NCB * NBKT;     // 3.2 MB

    // bucket build + degree + CSR sort
    k_zero_scal<<<1, 64, 0, stream>>>(scal);
    k_count<<<NCB, 256, 0, stream>>>(dst, counts);
    k_colsum<<<(NBKT + 255) / 256, 256, 0, stream>>>(counts, total);
    k_scan<<<1, 1024, 0, stream>>>(total, startb);
    k_base<<<(NBKT + 255) / 256, 256, 0, stream>>>(counts, startb, basea);
    k_scatter<<<NCB, 256, 0, stream>>>(src, dst, w, basea, rec);
    k_deg<<<NBKT, 256, 0, stream>>>(rec, startb, dinv);
    k_sort<<<NBKT, 256, 0, stream>>>(rec, startb, dinv, nodeptr);

    // layer 1 dense (fp16 out)
    k_xform64<<<(NN + 63) / 64, 256, 0, stream>>>(x, W1, bufA);
    // layer 1 agg + fused relu + W2 (fp16 in/out)
    k_agg16_l1<<<NBLK_AGG, 256, 0, stream>>>(rec, nodeptr, dinv, bufA, b1, W2, bufC);
    // layer 2 agg + fused relu + W3 dot + pool partials
    k_agg16_l2<<<NBLK_AGG, 256, 0, stream>>>(rec, nodeptr, dinv, bufC, b2, W3, clin, partials);
    // grid-wide partials reduction (fixes the 100us single-block serial reduce)
    k_psum<<<64, 256, 0, stream>>>(partials, scal + 2);
    // layer 3 scalar agg + fused max
    k_aggc<<<NN / 32, 256, 0, stream>>>(rec, nodeptr, dinv, clin, b3, cbuf, (unsigned*)scal);

    // softmax + value
    k_exp<<<512, 256, 0, stream>>>(cbuf, (const unsigned*)scal, out, scal + 1);
    k_final<<<512, 256, 0, stream>>>(out, scal + 1, scal + 2, A2w, A2b);
}

// Round 12
// 391.341 us; speedup vs baseline: 1.4738x; 1.2427x over previous
//
#include <hip/hip_runtime.h>
#include <hip/hip_fp16.h>
#include <math.h>

#define NN 100000
#define NE 3200000
#define NBKT 782            // ceil(100000 / 128) buckets of 128 dst nodes
#define NCB 1024            // count/scatter blocks
#define CHUNK 3125          // NE / NCB exactly
#define CAP 4608            // max edges per bucket (mean 4092 -> +8 sigma)
#define NBLK_AGG (NN / 16)  // 6250

// ---------------- helpers ----------------

__device__ __forceinline__ uint2 ntload_u2(const uint2* p) {
    unsigned long long v = __builtin_nontemporal_load((const unsigned long long*)p);
    return make_uint2((unsigned)(v & 0xffffffffu), (unsigned)(v >> 32));
}

// ---------------- small init ----------------

__global__ void k_zero_scal(float* __restrict__ scal) {
    if (threadIdx.x < 32) scal[threadIdx.x] = 0.0f;
}

// ---------------- bucket build ----------------

__global__ __launch_bounds__(256) void k_count(const int* __restrict__ dst,
                                               int* __restrict__ counts) {
    __shared__ int hist[NBKT];
    for (int t = threadIdx.x; t < NBKT; t += 256) hist[t] = 0;
    __syncthreads();
    int e0 = blockIdx.x * CHUNK;
    for (int j = threadIdx.x; j < CHUNK; j += 256)
        atomicAdd(&hist[__builtin_nontemporal_load(&dst[e0 + j]) >> 7], 1);
    __syncthreads();
    for (int t = threadIdx.x; t < NBKT; t += 256)
        counts[blockIdx.x * NBKT + t] = hist[t];
}

// total[bin] = sum over blocks  (grid = NBKT blocks)
__global__ __launch_bounds__(256) void k_colsum(const int* __restrict__ counts,
                                                int* __restrict__ total) {
    __shared__ float lds[256];
    int bin = blockIdx.x;
    int s = 0;
    for (int b = threadIdx.x; b < NCB; b += 256) s += counts[b * NBKT + bin];
    lds[threadIdx.x] = (float)s;
    __syncthreads();
    for (int st = 128; st > 0; st >>= 1) {
        if (threadIdx.x < st) lds[threadIdx.x] += lds[threadIdx.x + st];
        __syncthreads();
    }
    if (threadIdx.x == 0) total[bin] = (int)lds[0];
}

__global__ void k_scan(const int* __restrict__ total, int* __restrict__ start) {
    __shared__ int a[1024];
    int t = threadIdx.x;
    int mine = (t < NBKT) ? total[t] : 0;
    a[t] = mine;
    for (int off = 1; off < 1024; off <<= 1) {
        __syncthreads();
        int v = a[t] + ((t >= off) ? a[t - off] : 0);
        __syncthreads();
        a[t] = v;
    }
    __syncthreads();
    if (t < NBKT) start[t] = a[t] - mine;        // exclusive
    if (t == 0) start[NBKT] = NE;
}

// base[b][bin] = start[bin] + prefix_b(counts[.][bin])   (grid = NBKT blocks)
__global__ __launch_bounds__(256) void k_base(const int* __restrict__ counts,
                                              const int* __restrict__ start,
                                              int* __restrict__ base) {
    __shared__ int vals[NCB];     // 4 KB
    __shared__ int tsum[256];
    int bin = blockIdx.x;
    for (int b = threadIdx.x; b < NCB; b += 256) vals[b] = counts[b * NBKT + bin];
    __syncthreads();
    int b0 = threadIdx.x * 4;     // NCB == 4*256 exactly
    int c0 = vals[b0], c1 = vals[b0 + 1], c2 = vals[b0 + 2], c3 = vals[b0 + 3];
    int sum = c0 + c1 + c2 + c3;
    tsum[threadIdx.x] = sum;
    __syncthreads();
    for (int off = 1; off < 256; off <<= 1) {
        int v = tsum[threadIdx.x];
        if (threadIdx.x >= off) v += tsum[threadIdx.x - off];
        __syncthreads();
        tsum[threadIdx.x] = v;
        __syncthreads();
    }
    int excl = tsum[threadIdx.x] - sum + start[bin];
    base[(b0 + 0) * NBKT + bin] = excl;
    base[(b0 + 1) * NBKT + bin] = excl + c0;
    base[(b0 + 2) * NBKT + bin] = excl + c0 + c1;
    base[(b0 + 3) * NBKT + bin] = excl + c0 + c1 + c2;
}

// ---------------- sorted-write scatter ----------------
// Stage the block's 3125-edge chunk in LDS, counting-sort by bucket, write
// bucket-runs contiguously (coalesced) into rec at base[blk][bin].

__global__ __launch_bounds__(256) void k_scatter(const int* __restrict__ src,
                                                 const int* __restrict__ dst,
                                                 const float* __restrict__ w,
                                                 const int* __restrict__ base,
                                                 uint2* __restrict__ rec) {
    __shared__ uint2 stage[CHUNK];            // 25.0 KB
    __shared__ uint2 sorted[CHUNK];           // 25.0 KB
    __shared__ unsigned short sbin[CHUNK];    // 6.25 KB
    __shared__ unsigned short sbin2[CHUNK];   // 6.25 KB
    __shared__ int hist[NBKT];                // 3.1 KB
    __shared__ int lofs[NBKT];                // 3.1 KB
    __shared__ int cur[NBKT];                 // 3.1 KB
    __shared__ int tsum[256];
    int b = blockIdx.x;
    int e0 = b * CHUNK;
    for (int t = threadIdx.x; t < NBKT; t += 256) hist[t] = 0;
    __syncthreads();
    // pass A: stage + histogram
    for (int j = threadIdx.x; j < CHUNK; j += 256) {
        int d = __builtin_nontemporal_load(&dst[e0 + j]);
        int s = __builtin_nontemporal_load(&src[e0 + j]);
        float we = __builtin_nontemporal_load(&w[e0 + j]);
        int bin = d >> 7;
        stage[j] = make_uint2(((unsigned)s << 7) | (unsigned)(d & 127),
                              __float_as_uint(we));
        sbin[j] = (unsigned short)bin;
        atomicAdd(&hist[bin], 1);
    }
    __syncthreads();
    // exclusive scan hist -> lofs (4 bins per thread)
    int bb = threadIdx.x * 4;
    int h0 = (bb + 0 < NBKT) ? hist[bb + 0] : 0;
    int h1 = (bb + 1 < NBKT) ? hist[bb + 1] : 0;
    int h2 = (bb + 2 < NBKT) ? hist[bb + 2] : 0;
    int h3 = (bb + 3 < NBKT) ? hist[bb + 3] : 0;
    int sum = h0 + h1 + h2 + h3;
    tsum[threadIdx.x] = sum;
    __syncthreads();
    for (int off = 1; off < 256; off <<= 1) {
        int v = tsum[threadIdx.x];
        if (threadIdx.x >= off) v += tsum[threadIdx.x - off];
        __syncthreads();
        tsum[threadIdx.x] = v;
        __syncthreads();
    }
    int excl = tsum[threadIdx.x] - sum;
    if (bb + 0 < NBKT) { lofs[bb + 0] = excl;               cur[bb + 0] = excl; }
    if (bb + 1 < NBKT) { lofs[bb + 1] = excl + h0;          cur[bb + 1] = excl + h0; }
    if (bb + 2 < NBKT) { lofs[bb + 2] = excl + h0 + h1;     cur[bb + 2] = excl + h0 + h1; }
    if (bb + 3 < NBKT) { lofs[bb + 3] = excl + h0 + h1 + h2; cur[bb + 3] = excl + h0 + h1 + h2; }
    __syncthreads();
    // pass B: permute into sorted order (by bucket)
    for (int j = threadIdx.x; j < CHUNK; j += 256) {
        int bin = sbin[j];
        int r = atomicAdd(&cur[bin], 1);
        sorted[r] = stage[j];
        sbin2[r] = (unsigned short)bin;
    }
    __syncthreads();
    // gbase[bin] = global base - local base  (reuse cur)
    for (int t = threadIdx.x; t < NBKT; t += 256)
        cur[t] = base[b * NBKT + t] - lofs[t];
    __syncthreads();
    // pass C: contiguous-run writes
    for (int j = threadIdx.x; j < CHUNK; j += 256) {
        int bin = sbin2[j];
        rec[cur[bin] + j] = sorted[j];
    }
}

// ---------------- in-bucket counting sort -> CSR, fused degree/dinv ----------------
// Output record: (src, nw = w * dinv[dst]).  dinv computed here from staged w sums.

__global__ void k_sort(uint2* __restrict__ rec, const int* __restrict__ start,
                       float* __restrict__ dinv_g, int* __restrict__ nodeptr) {
    __shared__ uint2 buf[CAP];
    __shared__ int hist[128];
    __shared__ int scn[128];
    __shared__ int cur[128];
    __shared__ float dacc[128];
    __shared__ float dloc[128];
    int bin = blockIdx.x;
    int base_node = bin << 7;
    int nNodes = min(128, NN - base_node);
    int e0 = start[bin], e1 = start[bin + 1];
    int cnt = e1 - e0;
    if (cnt > CAP) cnt = CAP;
    if (threadIdx.x < 128) {
        hist[threadIdx.x] = 0;
        dacc[threadIdx.x] = 0.0f;
    }
    __syncthreads();
    for (int j = threadIdx.x; j < cnt; j += 256) {
        uint2 r = ntload_u2(&rec[e0 + j]);
        buf[j] = r;
        int dl = r.x & 127;
        atomicAdd(&hist[dl], 1);
        atomicAdd(&dacc[dl], __uint_as_float(r.y));
    }
    __syncthreads();
    if (threadIdx.x < 128) {
        float d = rsqrtf(1.0f + dacc[threadIdx.x]);   // deg >= 1 (self-loop)
        dloc[threadIdx.x] = d;
        if (threadIdx.x < nNodes) dinv_g[base_node + threadIdx.x] = d;
        scn[threadIdx.x] = hist[threadIdx.x];
    }
    __syncthreads();
    for (int off = 1; off < 128; off <<= 1) {
        int v = 0;
        if (threadIdx.x < 128) {
            v = scn[threadIdx.x];
            if (threadIdx.x >= off) v += scn[threadIdx.x - off];
        }
        __syncthreads();
        if (threadIdx.x < 128) scn[threadIdx.x] = v;
        __syncthreads();
    }
    if (threadIdx.x < 128) {
        int excl = scn[threadIdx.x] - hist[threadIdx.x];
        cur[threadIdx.x] = excl;
        if (threadIdx.x < nNodes) nodeptr[base_node + threadIdx.x] = e0 + excl;
    }
    if (bin == NBKT - 1 && threadIdx.x == 0) nodeptr[NN] = e1;
    __syncthreads();
    for (int j = threadIdx.x; j < cnt; j += 256) {
        uint2 r = buf[j];
        int s = (int)(r.x >> 7);
        int dl = r.x & 127;
        int pos = atomicAdd(&cur[dl], 1);
        float nw = __uint_as_float(r.y) * dloc[dl];   // w * dinv[dst] only
        rec[e0 + pos] = make_uint2((unsigned)s, __float_as_uint(nw));
    }
}

// ---------------- dense transform layer 1 (writes h1' = dinv * x@W1^T, fp16) ----------------

__global__ __launch_bounds__(256) void k_xform64(const float* __restrict__ x,
                                                 const float* __restrict__ W,
                                                 const float* __restrict__ dinv,
                                                 __half* __restrict__ out) {
    __shared__ float xs[64 * 68];
    __shared__ float Wsh[16 * 68];
    int row0 = blockIdx.x * 64;
    for (int idx = threadIdx.x; idx < 1024; idx += 256)
        Wsh[(idx >> 6) * 68 + (idx & 63)] = W[idx];
    for (int idx = threadIdx.x; idx < 1024; idx += 256) {
        int r = idx >> 4, c4 = idx & 15;
        float4 v = make_float4(0.f, 0.f, 0.f, 0.f);
        if (row0 + r < NN)
            v = *(const float4*)(x + (size_t)(row0 + r) * 64 + c4 * 4);
        *(float4*)&xs[r * 68 + c4 * 4] = v;
    }
    __syncthreads();
    int f = threadIdx.x & 15, rg = threadIdx.x >> 4;
    float a0 = 0.f, a1 = 0.f, a2 = 0.f, a3 = 0.f;
#pragma unroll
    for (int k4 = 0; k4 < 16; ++k4) {
        float4 wv = *(float4*)&Wsh[f * 68 + k4 * 4];
        float4 x0 = *(float4*)&xs[(rg * 4 + 0) * 68 + k4 * 4];
        float4 x1 = *(float4*)&xs[(rg * 4 + 1) * 68 + k4 * 4];
        float4 x2 = *(float4*)&xs[(rg * 4 + 2) * 68 + k4 * 4];
        float4 x3 = *(float4*)&xs[(rg * 4 + 3) * 68 + k4 * 4];
        a0 += x0.x * wv.x + x0.y * wv.y + x0.z * wv.z + x0.w * wv.w;
        a1 += x1.x * wv.x + x1.y * wv.y + x1.z * wv.z + x1.w * wv.w;
        a2 += x2.x * wv.x + x2.y * wv.y + x2.z * wv.z + x2.w * wv.w;
        a3 += x3.x * wv.x + x3.y * wv.y + x3.z * wv.z + x3.w * wv.w;
    }
    int br = row0 + rg * 4;
    if (br + 0 < NN) out[(br + 0) * 16 + f] = __float2half(a0 * dinv[br + 0]);
    if (br + 1 < NN) out[(br + 1) * 16 + f] = __float2half(a1 * dinv[br + 1]);
    if (br + 2 < NN) out[(br + 2) * 16 + f] = __float2half(a2 * dinv[br + 2]);
    if (br + 3 < NN) out[(br + 3) * 16 + f] = __float2half(a3 * dinv[br + 3]);
}

// ---------------- edge-gather core (unroll-8 software pipeline) ----------------

__device__ __forceinline__ float edge_gather16(const uint2* __restrict__ rec,
                                               int e0, int e1, int f,
                                               const __half* __restrict__ h,
                                               float acc) {
    int j = e0;
    uint2 p[8];
    if (j + 8 <= e1) {
#pragma unroll
        for (int t = 0; t < 8; ++t) p[t] = ntload_u2(&rec[j + t]);
        j += 8;
        for (; j + 8 <= e1; j += 8) {
            uint2 q[8];
#pragma unroll
            for (int t = 0; t < 8; ++t) q[t] = ntload_u2(&rec[j + t]);
#pragma unroll
            for (int t = 0; t < 8; ++t)
                acc += __uint_as_float(p[t].y) * __half2float(h[p[t].x * 16 + f]);
#pragma unroll
            for (int t = 0; t < 8; ++t) p[t] = q[t];
        }
#pragma unroll
        for (int t = 0; t < 8; ++t)
            acc += __uint_as_float(p[t].y) * __half2float(h[p[t].x * 16 + f]);
    }
    for (; j < e1; ++j) {
        uint2 r = ntload_u2(&rec[j]);
        acc += __uint_as_float(r.y) * __half2float(h[r.x * 16 + f]);
    }
    return acc;
}

// ---------------- layer 1: CSR agg + fused relu + W2; writes h2' = dinv*o2lin ----------------

__global__ __launch_bounds__(256) void k_agg16_l1(const uint2* __restrict__ rec,
                                                  const int* __restrict__ nodeptr,
                                                  const float* __restrict__ dinv,
                                                  const __half* __restrict__ h,
                                                  const float* __restrict__ b1,
                                                  const float* __restrict__ W2,
                                                  __half* __restrict__ outC) {
    __shared__ float W2s[16 * 17];
    for (int idx = threadIdx.x; idx < 256; idx += 256)
        W2s[(idx >> 4) * 17 + (idx & 15)] = W2[idx];
    __syncthreads();
    int f = threadIdx.x & 15;
    int n = blockIdx.x * 16 + (threadIdx.x >> 4);
    int e0 = nodeptr[n], e1 = nodeptr[n + 1];
    float di = dinv[n];
    float acc = b1[f] + di * __half2float(h[n * 16 + f]);   // dinv^2 h = dinv * h'
    acc = edge_gather16(rec, e0, e1, f, h, acc);
    float rl = fmaxf(acc, 0.0f);
    float a2 = 0.0f;
#pragma unroll
    for (int k = 0; k < 16; ++k)
        a2 += __shfl(rl, k, 16) * W2s[f * 17 + k];
    outC[n * 16 + f] = __float2half(a2 * di);               // fold dinv for next layer
}

// ---------------- layer 2: CSR agg + relu + W3 dot + pool partials ----------------

__global__ __launch_bounds__(256) void k_agg16_l2(const uint2* __restrict__ rec,
                                                  const int* __restrict__ nodeptr,
                                                  const float* __restrict__ dinv,
                                                  const __half* __restrict__ h,
                                                  const float* __restrict__ b2,
                                                  const float* __restrict__ W3,
                                                  float* __restrict__ clin,
                                                  float* __restrict__ partials) {
    __shared__ float lds[256];
    int f = threadIdx.x & 15;
    int n = blockIdx.x * 16 + (threadIdx.x >> 4);
    int e0 = nodeptr[n], e1 = nodeptr[n + 1];
    float di = dinv[n];
    float acc = b2[f] + di * __half2float(h[n * 16 + f]);
    acc = edge_gather16(rec, e0, e1, f, h, acc);
    float rl = fmaxf(acc, 0.0f);                            // relu(o2): pool uses this
    float s = rl * W3[f];
    s += __shfl_xor(s, 8, 16);
    s += __shfl_xor(s, 4, 16);
    s += __shfl_xor(s, 2, 16);
    s += __shfl_xor(s, 1, 16);
    if (f == 0) clin[n] = s * di;                           // clin' = dinv * (relu.W3)
    lds[threadIdx.x] = rl;
    __syncthreads();
    for (int st = 128; st >= 16; st >>= 1) {
        if (threadIdx.x < st) lds[threadIdx.x] += lds[threadIdx.x + st];
        __syncthreads();
    }
    if (threadIdx.x < 16) partials[blockIdx.x * 16 + threadIdx.x] = lds[threadIdx.x];
}

// ---------------- partials reduction ----------------

__global__ __launch_bounds__(256) void k_psum(const float* __restrict__ partials,
                                              float* __restrict__ hsum) {
    __shared__ float lds[256];
    int f = threadIdx.x & 15, g = threadIdx.x >> 4;
    const int rows_per_blk = (NBLK_AGG + 63) / 64;
    int r0 = blockIdx.x * rows_per_blk;
    int r1 = min(r0 + rows_per_blk, NBLK_AGG);
    float s = 0.0f;
    for (int i = r0 + g; i < r1; i += 16) s += partials[i * 16 + f];
    lds[threadIdx.x] = s;
    __syncthreads();
    for (int st = 128; st >= 16; st >>= 1) {
        if (threadIdx.x < st) lds[threadIdx.x] += lds[threadIdx.x + st];
        __syncthreads();
    }
    if (threadIdx.x < 16) atomicAdd(&hsum[threadIdx.x], lds[threadIdx.x]);
}

// ---------------- layer 3 scalar aggregation + fused max ----------------

__device__ __forceinline__ unsigned fkey(float x) {
    unsigned b = __float_as_uint(x);
    return (b & 0x80000000u) ? ~b : (b | 0x80000000u);
}
__device__ __forceinline__ float fdecode(unsigned u) {
    unsigned b = (u & 0x80000000u) ? (u & 0x7FFFFFFFu) : ~u;
    return __uint_as_float(b);
}

__global__ __launch_bounds__(256) void k_aggc(const uint2* __restrict__ rec,
                                              const int* __restrict__ nodeptr,
                                              const float* __restrict__ dinv,
                                              const float* __restrict__ clin,
                                              const float* __restrict__ b3,
                                              float* __restrict__ c,
                                              unsigned* __restrict__ maxkey) {
    __shared__ float smax[32];
    int lane = threadIdx.x & 7;
    int g = threadIdx.x >> 3;
    int n = blockIdx.x * 32 + g;
    int e0 = nodeptr[n], e1 = nodeptr[n + 1];
    float acc = 0.0f;
    int j = e0 + lane;
    if (j < e1) {
        uint2 p = ntload_u2(&rec[j]);
        j += 8;
        while (j < e1) {
            uint2 q = ntload_u2(&rec[j]);
            j += 8;
            acc += __uint_as_float(p.y) * clin[p.x];
            p = q;
        }
        acc += __uint_as_float(p.y) * clin[p.x];
    }
    acc += __shfl_down(acc, 4, 8);
    acc += __shfl_down(acc, 2, 8);
    acc += __shfl_down(acc, 1, 8);
    if (lane == 0) {
        float di = dinv[n];
        float cv = b3[0] + di * clin[n] + acc;   // dinv^2 clin = dinv * clin'
        c[n] = cv;
        smax[g] = cv;
    }
    __syncthreads();
    if (threadIdx.x < 32) {
        float m = smax[threadIdx.x];
        m = fmaxf(m, __shfl_xor(m, 16, 32));
        m = fmaxf(m, __shfl_xor(m, 8, 32));
        m = fmaxf(m, __shfl_xor(m, 4, 32));
        m = fmaxf(m, __shfl_xor(m, 2, 32));
        m = fmaxf(m, __shfl_xor(m, 1, 32));
        if (threadIdx.x == 0) atomicMax(maxkey, fkey(m));
    }
}

// ---------------- softmax ----------------

__global__ void k_exp(const float* __restrict__ c, const unsigned* __restrict__ maxkey,
                      float* __restrict__ outp, float* __restrict__ sumexp) {
    __shared__ float lds[256];
    float mx = fdecode(*maxkey);
    float s = 0.0f;
    for (int i = blockIdx.x * 256 + threadIdx.x; i < NN; i += gridDim.x * 256) {
        float p = expf(c[i] - mx);
        outp[i] = p;
        s += p;
    }
    lds[threadIdx.x] = s;
    __syncthreads();
    for (int t = 128; t > 0; t >>= 1) {
        if (threadIdx.x < t) lds[threadIdx.x] += lds[threadIdx.x + t];
        __syncthreads();
    }
    if (threadIdx.x == 0) atomicAdd(sumexp, lds[0]);
}

__global__ void k_final(float* __restrict__ out, const float* __restrict__ sumexp,
                        const float* __restrict__ hsum, const float* __restrict__ A2w,
                        const float* __restrict__ A2b) {
    float inv = 1.0f / (*sumexp);
    for (int i = blockIdx.x * 256 + threadIdx.x; i < NN; i += gridDim.x * 256)
        out[i] *= inv;
    if (blockIdx.x == 0 && threadIdx.x == 0) {
        float v = 0.0f;
#pragma unroll
        for (int f = 0; f < 16; ++f) v += hsum[f] * (1.0f / (float)NN) * A2w[f];
        out[NN] = v + A2b[0];
    }
}

// ---------------- launch ----------------

extern "C" void kernel_launch(void* const* d_in, const int* in_sizes, int n_in,
                              void* d_out, int out_size, void* d_ws, size_t ws_size,
                              hipStream_t stream) {
    const float* x   = (const float*)d_in[0];
    const int*   src = (const int*)d_in[1];
    const int*   dst = ((const int*)d_in[1]) + NE;
    const float* w   = (const float*)d_in[2];
    const float* W1  = (const float*)d_in[3];
    const float* b1  = (const float*)d_in[4];
    const float* W2  = (const float*)d_in[5];
    const float* b2  = (const float*)d_in[6];
    const float* W3  = (const float*)d_in[7];
    const float* b3  = (const float*)d_in[8];
    const float* A2w = (const float*)d_in[9];
    const float* A2b = (const float*)d_in[10];
    float* out = (float*)d_out;

    // workspace layout
    float* cur = (float*)d_ws;
    uint2*  rec     = (uint2*)cur;      cur += 2 * (size_t)NE;   // 25.6 MB
    float*  dinv    = cur;              cur += NN;
    __half* bufA    = (__half*)cur;     cur += NN * 8;           // NN*16 fp16
    __half* bufC    = (__half*)cur;     cur += NN * 8;           // NN*16 fp16
    float*  clin    = cur;              cur += NN;
    float*  cbuf    = cur;              cur += NN;
    float*  scal    = cur;              cur += 32;   // [0]=maxkey [1]=sumexp [2..17]=hsum
    int*    total   = (int*)cur;        cur += NBKT;
    int*    startb  = (int*)cur;        cur += NBKT + 1;
    int*    nodeptr = (int*)cur;        cur += NN + 1;
    float*  partials= cur;              cur += (size_t)NBLK_AGG * 16;  // 400 KB
    int*    counts  = (int*)cur;        cur += (size_t)NCB * NBKT;     // 3.2 MB
    int*    basea   = (int*)cur;        cur += (size_t)NCB * NBKT;     // 3.2 MB

    // bucket build + CSR sort (degree fused into sort)
    k_zero_scal<<<1, 64, 0, stream>>>(scal);
    k_count<<<NCB, 256, 0, stream>>>(dst, counts);
    k_colsum<<<NBKT, 256, 0, stream>>>(counts, total);
    k_scan<<<1, 1024, 0, stream>>>(total, startb);
    k_base<<<NBKT, 256, 0, stream>>>(counts, startb, basea);
    k_scatter<<<NCB, 256, 0, stream>>>(src, dst, w, basea, rec);
    k_sort<<<NBKT, 256, 0, stream>>>(rec, startb, dinv, nodeptr);

    // layer 1 dense (h1' = dinv * xW1, fp16)
    k_xform64<<<(NN + 63) / 64, 256, 0, stream>>>(x, W1, dinv, bufA);
    // layer 1 agg + fused relu + W2 (h2' = dinv * o2lin)
    k_agg16_l1<<<NBLK_AGG, 256, 0, stream>>>(rec, nodeptr, dinv, bufA, b1, W2, bufC);
    // layer 2 agg + fused relu + W3 dot + pool partials (clin' = dinv * clin)
    k_agg16_l2<<<NBLK_AGG, 256, 0, stream>>>(rec, nodeptr, dinv, bufC, b2, W3, clin, partials);
    // partials reduction
    k_psum<<<64, 256, 0, stream>>>(partials, scal + 2);
    // layer 3 scalar agg + fused max
    k_aggc<<<NN / 32, 256, 0, stream>>>(rec, nodeptr, dinv, clin, b3, cbuf, (unsigned*)scal);

    // softmax + value
    k_exp<<<512, 256, 0, stream>>>(cbuf, (const unsigned*)scal, out, scal + 1);
    k_final<<<512, 256, 0, stream>>>(out, scal + 1, scal + 2, A2w, A2b);
}